// Round 20
// baseline (3556.332 us; speedup 1.0000x reference)
//
#include <hip/hip_runtime.h>

// VQ-VAE vector quantizer, MI355X. N=32768 rows, D=128, K=8192 codes.
// Round 20 = r19 with LANE-PRIVATE prefix runmax in vq_screen: no cross-lane
// shfl/reduce at all (r19 showed the shfl latency chain, not bank conflicts,
// was the cost). Each lane tracks the prefix max over its own 8 codes/chunk;
// export when lane-chunk-max + DELTA > private runmax. Any prefix lower
// bound on the row max keeps the export superset (argmin_dot >= M_global -
// 3.4e-5 > prefix - DELTA). E[exports/row-half] ~ 20-28 << HCAP=64; proven
// per-half fallback regardless. Pair batching reverted (purposeless without
// shfls). Staging cadence (ring-4 + prefetch-2 + counted vmcnt), rescore,
// cvt, finalize verbatim r19 (r1/r3-proven numpy-bit-exact chain).

#define KC   8192
#define DIM  128
#define NR   32768

// d_out layout (flat, reference return order, all f32)
#define O_ZQ   0
#define O_LOSS 4194304
#define O_IDX  4194305
#define O_NSZ  4227073
#define O_NSUM 4235265
#define O_NEMB 5283841
// scratch aliases inside d_out (overwritten by later kernels):
#define O_EBF  5283844   // e_bf16 (2MB), inside O_NEMB
// cand32 u32[32768*128] fills O_ZQ exactly; z_q overwrites row-by-row after
// that row's list is consumed (same-wave read-before-write, r10-proven).

// ws layout (f32 index units)
#define W_LOSSP 16       // [16, 272): 256 loss buckets
#define W_CNT   8192     // u32[32768]: lo16 = half0 count, hi16 = half1 count
#define W_ZBF   49152    // z_bf16 (8MB), 16B-aligned
#define HCAP    64

#define DELTA    1.5e-4f   // export guard; >= 4x (2*bf16err + tie-span)
#define DWIN     64        // dot16 filter window (1.22e-4)
#define FLOATMAX 3.402823466e+38f

using short8 = __attribute__((ext_vector_type(8))) short;   // 8 bf16
using f32x4  = __attribute__((ext_vector_type(4))) float;

static __device__ __forceinline__ unsigned int pack2_bf16(float lo, float hi) {
    unsigned int ul = __builtin_bit_cast(unsigned int, lo);
    unsigned int uh = __builtin_bit_cast(unsigned int, hi);
    ul = (ul + 0x7fffu + ((ul >> 16) & 1u)) >> 16;   // RNE to bf16
    uh = (uh + 0x7fffu + ((uh >> 16) & 1u)) >> 16;
    return ul | (uh << 16);
}

// ---------------------------------------------------------------------------
// cvt + init: z->bf16 (ws), embed->bf16, seed new_size/new_sum, zero cnt
// and loss buckets.
// ---------------------------------------------------------------------------
__global__ __launch_bounds__(256)
void vq_cvt(const float* __restrict__ z, const float* __restrict__ embed,
            const float* __restrict__ cs, const float* __restrict__ ea,
            float* __restrict__ out, float* __restrict__ ws) {
    int gid = blockIdx.x * 256 + threadIdx.x;
    if (gid < 524288) {
        const float4* s = (const float4*)z + (size_t)gid * 2;
        float4 a = s[0], b = s[1];
        uint4 wv;
        wv.x = pack2_bf16(a.x, a.y); wv.y = pack2_bf16(a.z, a.w);
        wv.z = pack2_bf16(b.x, b.y); wv.w = pack2_bf16(b.z, b.w);
        ((uint4*)(ws + W_ZBF))[gid] = wv;
    } else if (gid < 655360) {
        int j = gid - 524288;
        const float4* s = (const float4*)embed + (size_t)j * 2;
        float4 a = s[0], b = s[1];
        uint4 wv;
        wv.x = pack2_bf16(a.x, a.y); wv.y = pack2_bf16(a.z, a.w);
        wv.z = pack2_bf16(b.x, b.y); wv.w = pack2_bf16(b.z, b.w);
        ((uint4*)(out + O_EBF))[j] = wv;
    } else if (gid < 1703936) {
        int j = gid - 655360;
        out[O_NSUM + j] = 0.99f * ea[j];
    } else if (gid < 1712128) {
        int j = gid - 1703936;
        out[O_NSZ + j] = 0.99f * cs[j];
    } else if (gid < 1720320) {
        int j = gid - 1712128;
        ((uint4*)(ws + W_CNT))[j] = make_uint4(0u, 0u, 0u, 0u);
    } else if (gid < 1720576) {
        ws[W_LOSSP + (gid - 1720320)] = 0.f;
    }
}

// ---------------------------------------------------------------------------
// Screen (r5/r18 structure, lane-private runmax). Grid 512: block =
// (rb = bid>>1, cb = bid&1) -> 128 rows x 4096 codes, 64 chunks of 64 codes.
// 8 waves: chf = w&1, rh = w>>1 (32-row quarter), 2mf x 2nf tiles.
// Ring-4 LDS via global_load_lds (pre-swizzled source, wave-uniform dest),
// prefetch-2, counted vmcnt, one s_barrier per chunk. NO cross-lane ops:
// per-lane prefix runmax over the lane's own 8 codes/chunk; guarded export.
// ---------------------------------------------------------------------------
__global__ __launch_bounds__(512, 4)
void vq_screen(const uint4* __restrict__ zb4, const uint4* __restrict__ eb4,
               unsigned int* __restrict__ cnt, unsigned int* __restrict__ candg) {
    __shared__ uint4 els[4 * 1024];          // 4 x 16 KiB ring
    __shared__ unsigned int cnt_l[128];      // per-row export counters

    const int t    = threadIdx.x;
    const int lane = t & 63;
    const int w    = __builtin_amdgcn_readfirstlane(t >> 6);   // 0..7
    const int g    = lane >> 4;     // 0..3
    const int q    = lane & 15;     // 0..15
    const int chf  = w & 1;
    const int rh   = w >> 1;        // 0..3
    const int rb   = blockIdx.x >> 1;
    const int cb   = blockIdx.x & 1;
    const int row0 = rb * 128;

    if (t < 128) cnt_l[t] = 0u;

    // staging source (pre-swizzled: LDS slot (c,s) holds granule s^(c&7))
    const uint4* gsrc[2];
    #pragma unroll
    for (int i = 0; i < 2; ++i) {
        int c = w * 8 + i * 4 + g;                       // code-in-chunk 0..63
        gsrc[i] = eb4 + (size_t)cb * 65536 + c * 16 + (q ^ (c & 7));
    }

#define STAGE(CH)                                                             \
    {                                                                         \
        _Pragma("unroll")                                                     \
        for (int i = 0; i < 2; ++i)                                           \
            __builtin_amdgcn_global_load_lds(                                 \
                (const __attribute__((address_space(1))) unsigned int*)       \
                    (gsrc[i] + (size_t)(CH) * 1024),                          \
                (__attribute__((address_space(3))) unsigned int*)             \
                    &els[((CH) & 3) * 1024 + w * 128 + i * 64],               \
                16, 0, 0);                                                    \
    }

    float runmax[2] = { -FLOATMAX, -FLOATMAX };

    STAGE(0);
    STAGE(1);

    // x B-frags (chunk-invariant)
    short8 bx[2][4];
    #pragma unroll
    for (int nf = 0; nf < 2; ++nf) {
        const uint4* zp = zb4 + (size_t)(row0 + rh * 32 + nf * 16 + q) * 16;
        #pragma unroll
        for (int ks = 0; ks < 4; ++ks)
            bx[nf][ks] = __builtin_bit_cast(short8, zp[ks * 4 + g]);
    }

    for (int ch = 0; ch < 64; ++ch) {
        if (ch < 62) {
            STAGE(ch + 2);
            asm volatile("s_waitcnt vmcnt(4)" ::: "memory");
        } else if (ch == 62) {
            asm volatile("s_waitcnt vmcnt(2)" ::: "memory");
        } else {
            asm volatile("s_waitcnt vmcnt(0)" ::: "memory");
        }
        __builtin_amdgcn_s_barrier();

        const uint4* el = els + (ch & 3) * 1024;

        f32x4 acc[2][2];
        #pragma unroll
        for (int mf = 0; mf < 2; ++mf)
            #pragma unroll
            for (int nf = 0; nf < 2; ++nf) acc[mf][nf] = (f32x4)0.f;

        #pragma unroll
        for (int ks = 0; ks < 4; ++ks) {
            int k8 = ks * 4 + g;
            short8 af[2];
            #pragma unroll
            for (int mf = 0; mf < 2; ++mf) {
                int cm = chf * 32 + mf * 16 + q;
                af[mf] = __builtin_bit_cast(short8, el[cm * 16 + (k8 ^ (cm & 7))]);
            }
            #pragma unroll
            for (int mf = 0; mf < 2; ++mf)
                #pragma unroll
                for (int nf = 0; nf < 2; ++nf)
                    acc[mf][nf] = __builtin_amdgcn_mfma_f32_16x16x32_bf16(
                        af[mf], bx[nf][ks], acc[mf][nf], 0, 0, 0);
        }

        // epilogue: lane-private chunk max over own 8 codes, guarded export
        #pragma unroll
        for (int nf = 0; nf < 2; ++nf) {
            float cm = acc[0][nf][0];
            cm = fmaxf(cm, acc[0][nf][1]);
            cm = fmaxf(cm, acc[0][nf][2]);
            cm = fmaxf(cm, acc[0][nf][3]);
            cm = fmaxf(cm, acc[1][nf][0]);
            cm = fmaxf(cm, acc[1][nf][1]);
            cm = fmaxf(cm, acc[1][nf][2]);
            cm = fmaxf(cm, acc[1][nf][3]);

            bool scan = (cm + DELTA > runmax[nf]);
            runmax[nf] = fmaxf(runmax[nf], cm);
            if (scan) {
                float thr = runmax[nf] - DELTA;
                int r_l = rh * 32 + nf * 16 + q;
                #pragma unroll
                for (int mf = 0; mf < 2; ++mf)
                    #pragma unroll
                    for (int rg = 0; rg < 4; ++rg) {
                        if (acc[mf][nf][rg] > thr) {
                            int code = cb * 4096 + ch * 64 + chf * 32
                                     + mf * 16 + g * 4 + rg;
                            unsigned int dot16 = (unsigned int)(int)
                                fmaf(acc[mf][nf][rg], 524288.0f, 32768.0f);
                            unsigned int slot = atomicAdd(&cnt_l[r_l], 1u);
                            if (slot < HCAP)
                                candg[(size_t)(row0 + r_l) * 128 + cb * 64 + slot]
                                    = (unsigned int)code | (dot16 << 16);
                        }
                    }
            }
        }
    }
#undef STAGE

    __syncthreads();
    if (t < 128) {
        unsigned int v = min(cnt_l[t], (unsigned int)(HCAP + 1));
        atomicAdd(&cnt[row0 + t], v << (16 * cb));
    }
}

// ---------------------------------------------------------------------------
// Merged phase 2 (r10/r18-proven): dot16 DWIN filter -> exact rescore
// (numpy-bit-exact, r1/r3-proven) of survivors -> idx, z_q, loss partial,
// EMA stats. Overflowed half -> exact scan of its 4096 codes.
// ---------------------------------------------------------------------------
__global__ __launch_bounds__(256)
void vq_rescore_gather(const float* __restrict__ z,
                       const float* __restrict__ embed,
                       const unsigned int* __restrict__ cnt,
                       const unsigned int* __restrict__ candg,
                       float* __restrict__ out, float* __restrict__ ws) {
    __shared__ float xr[4][128];
    __shared__ float lsh[4];
    const int t = threadIdx.x, w = t >> 6, lane = t & 63;
    const int row = blockIdx.x * 4 + w;

    ((float2*)xr[w])[lane] = ((const float2*)(z + (size_t)row * DIM))[lane];
    __syncthreads();

    const float4* x4 = (const float4*)xr[w];

    float s1n;
    {
        #pragma clang fp contract(off)
        float r8[8];
        float4 a = x4[0], b = x4[1];
        r8[0] = a.x * a.x; r8[1] = a.y * a.y; r8[2] = a.z * a.z; r8[3] = a.w * a.w;
        r8[4] = b.x * b.x; r8[5] = b.y * b.y; r8[6] = b.z * b.z; r8[7] = b.w * b.w;
        for (int bb = 1; bb < 16; ++bb) {
            float4 c = x4[2 * bb], d = x4[2 * bb + 1];
            r8[0] += c.x * c.x; r8[1] += c.y * c.y; r8[2] += c.z * c.z; r8[3] += c.w * c.w;
            r8[4] += d.x * d.x; r8[5] += d.y * d.y; r8[6] += d.z * d.z; r8[7] += d.w * d.w;
        }
        s1n = ((r8[0] + r8[1]) + (r8[2] + r8[3])) + ((r8[4] + r8[5]) + (r8[6] + r8[7]));
    }

    float bd = FLOATMAX;
    int   bi = 0x7fffffff;

#define EVAL_CODE(code_)                                                      \
    {                                                                         \
        const float4* ep = (const float4*)(embed + (size_t)(code_) * DIM);    \
        float dot = 0.f;                                                      \
        _Pragma("unroll 8")                                                   \
        for (int k4 = 0; k4 < 32; ++k4) {                                     \
            float4 xv = x4[k4], ev = ep[k4];                                  \
            dot = fmaf(xv.x, ev.x, dot);                                      \
            dot = fmaf(xv.y, ev.y, dot);                                      \
            dot = fmaf(xv.z, ev.z, dot);                                      \
            dot = fmaf(xv.w, ev.w, dot);                                      \
        }                                                                     \
        float d = fmaf(-2.0f, dot, s1n);                                      \
        if (d < bd || (d == bd && (code_) < bi)) { bd = d; bi = (code_); }    \
    }

    const unsigned int v = cnt[row];
    const int c0 = (int)(v & 0xffffu);
    const int c1 = (int)(v >> 16);
    const bool ovf0 = (c0 > HCAP), ovf1 = (c1 > HCAP);

    const unsigned int* cl = candg + (size_t)row * 128;

    bool v0 = (!ovf0) && (lane < c0);
    bool v1 = (!ovf1) && (lane < c1);
    unsigned int p0 = v0 ? cl[lane] : 0u;
    unsigned int p1 = v1 ? cl[64 + lane] : 0u;
    int d0 = v0 ? (int)(p0 >> 16) : -1;
    int d1 = v1 ? (int)(p1 >> 16) : -1;

    int m = max(d0, d1);
    #pragma unroll
    for (int o = 32; o >= 1; o >>= 1) m = max(m, __shfl_xor(m, o, 64));

    if (v0 && d0 + DWIN >= m) { int code = (int)(p0 & 0xffffu); EVAL_CODE(code); }
    if (v1 && d1 + DWIN >= m) { int code = (int)(p1 & 0xffffu); EVAL_CODE(code); }

    if (ovf0) {
        for (int j = lane; j < 4096; j += 64) EVAL_CODE(j);
    }
    if (ovf1) {
        for (int j = lane; j < 4096; j += 64) { int code = 4096 + j; EVAL_CODE(code); }
    }
#undef EVAL_CODE

    #pragma unroll
    for (int o = 32; o >= 1; o >>= 1) {
        float d2 = __shfl_xor(bd, o, 64);
        int   i2 = __shfl_xor(bi, o, 64);
        if (d2 < bd || (d2 == bd && i2 < bi)) { bd = d2; bi = i2; }
    }

    float2 zv2 = ((const float2*)xr[w])[lane];
    float2 ev2 = ((const float2*)(embed + (size_t)bi * DIM))[lane];
    float2 o2;
    o2.x = zv2.x + (ev2.x - zv2.x);     // z + (z_q - z), np op order
    o2.y = zv2.y + (ev2.y - zv2.y);
    ((float2*)(out + O_ZQ))[(size_t)row * 64 + lane] = o2;

    float dx = zv2.x - ev2.x, dy = zv2.y - ev2.y;
    float lp = dx * dx + dy * dy;
    #pragma unroll
    for (int off = 32; off >= 1; off >>= 1) lp += __shfl_down(lp, off, 64);

    atomicAdd(&out[O_NSUM + (size_t)bi * DIM + lane * 2],     0.01f * zv2.x);
    atomicAdd(&out[O_NSUM + (size_t)bi * DIM + lane * 2 + 1], 0.01f * zv2.y);
    if (lane == 0) {
        out[O_IDX + row] = (float)bi;
        atomicAdd(&out[O_NSZ + bi], 0.01f);
        lsh[w] = lp;
    }
    __syncthreads();
    if (t == 0)
        atomicAdd(&ws[W_LOSSP + (blockIdx.x & 255)],
                  (lsh[0] + lsh[1]) + (lsh[2] + lsh[3]));
}

// ---------------------------------------------------------------------------
// finalize: n = sum(new_size) -> ws[1]; loss = sum(256 buckets)/(N*D)
// ---------------------------------------------------------------------------
__global__ __launch_bounds__(256)
void vq_finalize(float* __restrict__ out, float* __restrict__ ws) {
    __shared__ float sh[256];
    const int t = threadIdx.x;

    float s = 0.f;
    for (int i = t; i < KC; i += 256) s += out[O_NSZ + i];
    sh[t] = s; __syncthreads();
    for (int o = 128; o > 0; o >>= 1) {
        if (t < o) sh[t] += sh[t + o];
        __syncthreads();
    }
    float n = sh[0];
    __syncthreads();

    sh[t] = ws[W_LOSSP + t]; __syncthreads();
    for (int o = 128; o > 0; o >>= 1) {
        if (t < o) sh[t] += sh[t + o];
        __syncthreads();
    }
    if (t == 0) {
        ws[1] = n;
        out[O_LOSS] = sh[0] / 4194304.0f;
    }
}

__global__ __launch_bounds__(256)
void vq_new_embed(float* __restrict__ out, const float* __restrict__ ws) {
    int i = blockIdx.x * 256 + threadIdx.x;
    if (i >= KC * DIM) return;
    int k = i >> 7;
    float n  = ws[1];
    float ns = out[O_NSZ + k];
    float sm = (ns + 1e-5f) / (n + 0.08192f) * n;
    out[O_NEMB + i] = out[O_NSUM + i] / sm;
}

extern "C" void kernel_launch(void* const* d_in, const int* in_sizes, int n_in,
                              void* d_out, int out_size, void* d_ws, size_t ws_size,
                              hipStream_t stream) {
    const float* z     = (const float*)d_in[0];
    const float* embed = (const float*)d_in[1];
    const float* cs    = (const float*)d_in[2];
    const float* ea    = (const float*)d_in[3];
    float* out = (float*)d_out;
    float* ws  = (float*)d_ws;
    unsigned int* cnt   = (unsigned int*)(ws + W_CNT);
    unsigned int* candg = (unsigned int*)out;          // O_ZQ region (16MB)

    vq_cvt<<<6721, 256, 0, stream>>>(z, embed, cs, ea, out, ws);
    vq_screen<<<512, 512, 0, stream>>>((const uint4*)(ws + W_ZBF),
                                       (const uint4*)(out + O_EBF), cnt, candg);
    vq_rescore_gather<<<NR / 4, 256, 0, stream>>>(z, embed, cnt, candg, out, ws);
    vq_finalize<<<1, 256, 0, stream>>>(out, ws);
    vq_new_embed<<<4096, 256, 0, stream>>>(out, ws);
}

// Round 21
// 194.296 us; speedup vs baseline: 18.3036x; 18.3036x over previous
//
#include <hip/hip_runtime.h>

// VQ-VAE vector quantizer, MI355X. N=32768 rows, D=128, K=8192 codes.
// Round 21 = REVERT to r19 verbatim (measured best: 194us). r20's
// lane-private runmax created 8 export stripes/row-half -> candidate
// overflow -> mass fallback scans (rescore 3.5ms). r19's pair-epilogue
// wave-shared runmax (2 stripes/half) is the finest safe granularity.
// Screen: r5/r18 structure + pair-epilogue batching (shfls halved).
// Rescore: dot16 DWIN filter + numpy-bit-exact chain (r1/r3-proven),
// per-half fallback. cvt/finalize/new_embed unchanged.

#define KC   8192
#define DIM  128
#define NR   32768

// d_out layout (flat, reference return order, all f32)
#define O_ZQ   0
#define O_LOSS 4194304
#define O_IDX  4194305
#define O_NSZ  4227073
#define O_NSUM 4235265
#define O_NEMB 5283841
// scratch aliases inside d_out (overwritten by later kernels):
#define O_EBF  5283844   // e_bf16 (2MB), inside O_NEMB
// cand32 u32[32768*128] fills O_ZQ exactly; z_q overwrites row-by-row after
// that row's list is consumed (same-wave read-before-write, r10-proven).

// ws layout (f32 index units)
#define W_LOSSP 16       // [16, 272): 256 loss buckets
#define W_CNT   8192     // u32[32768]: lo16 = half0 count, hi16 = half1 count
#define W_ZBF   49152    // z_bf16 (8MB), 16B-aligned
#define HCAP    64

#define DELTA    1.5e-4f   // export guard; >= 4x (2*bf16err + tie-span)
#define DWIN     64        // dot16 filter window (1.22e-4)
#define FLOATMAX 3.402823466e+38f

using short8 = __attribute__((ext_vector_type(8))) short;   // 8 bf16
using f32x4  = __attribute__((ext_vector_type(4))) float;

static __device__ __forceinline__ unsigned int pack2_bf16(float lo, float hi) {
    unsigned int ul = __builtin_bit_cast(unsigned int, lo);
    unsigned int uh = __builtin_bit_cast(unsigned int, hi);
    ul = (ul + 0x7fffu + ((ul >> 16) & 1u)) >> 16;   // RNE to bf16
    uh = (uh + 0x7fffu + ((uh >> 16) & 1u)) >> 16;
    return ul | (uh << 16);
}

// ---------------------------------------------------------------------------
// cvt + init: z->bf16 (ws), embed->bf16, seed new_size/new_sum, zero cnt
// and loss buckets.
// ---------------------------------------------------------------------------
__global__ __launch_bounds__(256)
void vq_cvt(const float* __restrict__ z, const float* __restrict__ embed,
            const float* __restrict__ cs, const float* __restrict__ ea,
            float* __restrict__ out, float* __restrict__ ws) {
    int gid = blockIdx.x * 256 + threadIdx.x;
    if (gid < 524288) {
        const float4* s = (const float4*)z + (size_t)gid * 2;
        float4 a = s[0], b = s[1];
        uint4 wv;
        wv.x = pack2_bf16(a.x, a.y); wv.y = pack2_bf16(a.z, a.w);
        wv.z = pack2_bf16(b.x, b.y); wv.w = pack2_bf16(b.z, b.w);
        ((uint4*)(ws + W_ZBF))[gid] = wv;
    } else if (gid < 655360) {
        int j = gid - 524288;
        const float4* s = (const float4*)embed + (size_t)j * 2;
        float4 a = s[0], b = s[1];
        uint4 wv;
        wv.x = pack2_bf16(a.x, a.y); wv.y = pack2_bf16(a.z, a.w);
        wv.z = pack2_bf16(b.x, b.y); wv.w = pack2_bf16(b.z, b.w);
        ((uint4*)(out + O_EBF))[j] = wv;
    } else if (gid < 1703936) {
        int j = gid - 655360;
        out[O_NSUM + j] = 0.99f * ea[j];
    } else if (gid < 1712128) {
        int j = gid - 1703936;
        out[O_NSZ + j] = 0.99f * cs[j];
    } else if (gid < 1720320) {
        int j = gid - 1712128;
        ((uint4*)(ws + W_CNT))[j] = make_uint4(0u, 0u, 0u, 0u);
    } else if (gid < 1720576) {
        ws[W_LOSSP + (gid - 1720320)] = 0.f;
    }
}

// ---------------------------------------------------------------------------
// Screen (r5/r18 structure + pair epilogue). Grid 512: block = (rb = bid>>1,
// cb = bid&1) -> 128 rows x 4096 codes, 64 chunks of 64 codes processed in
// 32 pairs. 8 waves: chf = w&1, rh = w>>1 (32-row quarter), 2mf x 2nf tiles.
// Ring-4 LDS via global_load_lds (pre-swizzled source, wave-uniform dest),
// prefetch-2, counted vmcnt, one s_barrier per chunk (cadence unchanged).
// Cross-lane reduce + export scan once per PAIR. Private runmax stripes.
// ---------------------------------------------------------------------------
__global__ __launch_bounds__(512, 4)
void vq_screen(const uint4* __restrict__ zb4, const uint4* __restrict__ eb4,
               unsigned int* __restrict__ cnt, unsigned int* __restrict__ candg) {
    __shared__ uint4 els[4 * 1024];          // 4 x 16 KiB ring
    __shared__ unsigned int cnt_l[128];      // per-row export counters

    const int t    = threadIdx.x;
    const int lane = t & 63;
    const int w    = __builtin_amdgcn_readfirstlane(t >> 6);   // 0..7
    const int g    = lane >> 4;     // 0..3
    const int q    = lane & 15;     // 0..15
    const int chf  = w & 1;
    const int rh   = w >> 1;        // 0..3
    const int rb   = blockIdx.x >> 1;
    const int cb   = blockIdx.x & 1;
    const int row0 = rb * 128;

    if (t < 128) cnt_l[t] = 0u;

    // staging source (pre-swizzled: LDS slot (c,s) holds granule s^(c&7))
    const uint4* gsrc[2];
    #pragma unroll
    for (int i = 0; i < 2; ++i) {
        int c = w * 8 + i * 4 + g;                       // code-in-chunk 0..63
        gsrc[i] = eb4 + (size_t)cb * 65536 + c * 16 + (q ^ (c & 7));
    }

#define STAGE(CH)                                                             \
    {                                                                         \
        _Pragma("unroll")                                                     \
        for (int i = 0; i < 2; ++i)                                           \
            __builtin_amdgcn_global_load_lds(                                 \
                (const __attribute__((address_space(1))) unsigned int*)       \
                    (gsrc[i] + (size_t)(CH) * 1024),                          \
                (__attribute__((address_space(3))) unsigned int*)             \
                    &els[((CH) & 3) * 1024 + w * 128 + i * 64],               \
                16, 0, 0);                                                    \
    }

#define COMPUTE(CH, ACC)                                                      \
    {                                                                         \
        const uint4* el = els + ((CH) & 3) * 1024;                            \
        _Pragma("unroll")                                                     \
        for (int ks = 0; ks < 4; ++ks) {                                      \
            int k8 = ks * 4 + g;                                              \
            short8 af[2];                                                     \
            _Pragma("unroll")                                                 \
            for (int mf = 0; mf < 2; ++mf) {                                  \
                int cm = chf * 32 + mf * 16 + q;                              \
                af[mf] = __builtin_bit_cast(short8,                           \
                             el[cm * 16 + (k8 ^ (cm & 7))]);                  \
            }                                                                 \
            _Pragma("unroll")                                                 \
            for (int mf = 0; mf < 2; ++mf)                                    \
                _Pragma("unroll")                                             \
                for (int nf = 0; nf < 2; ++nf)                                \
                    ACC[mf][nf] = __builtin_amdgcn_mfma_f32_16x16x32_bf16(    \
                        af[mf], bx[nf][ks], ACC[mf][nf], 0, 0, 0);            \
        }                                                                     \
    }

    float runmax[2] = { -FLOATMAX, -FLOATMAX };

    STAGE(0);
    STAGE(1);

    // x B-frags (chunk-invariant)
    short8 bx[2][4];
    #pragma unroll
    for (int nf = 0; nf < 2; ++nf) {
        const uint4* zp = zb4 + (size_t)(row0 + rh * 32 + nf * 16 + q) * 16;
        #pragma unroll
        for (int ks = 0; ks < 4; ++ks)
            bx[nf][ks] = __builtin_bit_cast(short8, zp[ks * 4 + g]);
    }

    for (int ch = 0; ch < 64; ch += 2) {
        // ---- sub-iter A: chunk ch ----
        if (ch <= 60) {
            STAGE(ch + 2);
            asm volatile("s_waitcnt vmcnt(4)" ::: "memory");
        } else {  // ch == 62
            asm volatile("s_waitcnt vmcnt(2)" ::: "memory");
        }
        __builtin_amdgcn_s_barrier();

        f32x4 accA[2][2];
        #pragma unroll
        for (int mf = 0; mf < 2; ++mf)
            #pragma unroll
            for (int nf = 0; nf < 2; ++nf) accA[mf][nf] = (f32x4)0.f;
        COMPUTE(ch, accA);

        // ---- sub-iter B: chunk ch+1 ----
        if (ch <= 60) {
            STAGE(ch + 3);
            asm volatile("s_waitcnt vmcnt(4)" ::: "memory");
        } else {  // ch == 62 -> chunk 63 is the last
            asm volatile("s_waitcnt vmcnt(0)" ::: "memory");
        }
        __builtin_amdgcn_s_barrier();

        f32x4 accB[2][2];
        #pragma unroll
        for (int mf = 0; mf < 2; ++mf)
            #pragma unroll
            for (int nf = 0; nf < 2; ++nf) accB[mf][nf] = (f32x4)0.f;
        COMPUTE(ch + 1, accB);

        // ---- pair epilogue: reduce + guarded export over both chunks ----
        #pragma unroll
        for (int nf = 0; nf < 2; ++nf) {
            float cm = -FLOATMAX;
            #pragma unroll
            for (int mf = 0; mf < 2; ++mf)
                #pragma unroll
                for (int rg = 0; rg < 4; ++rg) {
                    cm = fmaxf(cm, accA[mf][nf][rg]);
                    cm = fmaxf(cm, accB[mf][nf][rg]);
                }
            cm = fmaxf(cm, __shfl_xor(cm, 16, 64));
            cm = fmaxf(cm, __shfl_xor(cm, 32, 64));

            bool scan = (cm + DELTA > runmax[nf]);
            runmax[nf] = fmaxf(runmax[nf], cm);
            if (scan) {
                float thr = runmax[nf] - DELTA;
                int r_l = rh * 32 + nf * 16 + q;
                #pragma unroll
                for (int mf = 0; mf < 2; ++mf)
                    #pragma unroll
                    for (int rg = 0; rg < 4; ++rg) {
                        if (accA[mf][nf][rg] > thr) {
                            int code = cb * 4096 + ch * 64 + chf * 32
                                     + mf * 16 + g * 4 + rg;
                            unsigned int dot16 = (unsigned int)(int)
                                fmaf(accA[mf][nf][rg], 524288.0f, 32768.0f);
                            unsigned int slot = atomicAdd(&cnt_l[r_l], 1u);
                            if (slot < HCAP)
                                candg[(size_t)(row0 + r_l) * 128 + cb * 64 + slot]
                                    = (unsigned int)code | (dot16 << 16);
                        }
                        if (accB[mf][nf][rg] > thr) {
                            int code = cb * 4096 + (ch + 1) * 64 + chf * 32
                                     + mf * 16 + g * 4 + rg;
                            unsigned int dot16 = (unsigned int)(int)
                                fmaf(accB[mf][nf][rg], 524288.0f, 32768.0f);
                            unsigned int slot = atomicAdd(&cnt_l[r_l], 1u);
                            if (slot < HCAP)
                                candg[(size_t)(row0 + r_l) * 128 + cb * 64 + slot]
                                    = (unsigned int)code | (dot16 << 16);
                        }
                    }
            }
        }
    }
#undef COMPUTE
#undef STAGE

    __syncthreads();
    if (t < 128) {
        unsigned int v = min(cnt_l[t], (unsigned int)(HCAP + 1));
        atomicAdd(&cnt[row0 + t], v << (16 * cb));
    }
}

// ---------------------------------------------------------------------------
// Merged phase 2 (r10/r18-proven): dot16 DWIN filter -> exact rescore
// (numpy-bit-exact, r1/r3-proven) of survivors -> idx, z_q, loss partial,
// EMA stats. Overflowed half -> exact scan of its 4096 codes.
// ---------------------------------------------------------------------------
__global__ __launch_bounds__(256)
void vq_rescore_gather(const float* __restrict__ z,
                       const float* __restrict__ embed,
                       const unsigned int* __restrict__ cnt,
                       const unsigned int* __restrict__ candg,
                       float* __restrict__ out, float* __restrict__ ws) {
    __shared__ float xr[4][128];
    __shared__ float lsh[4];
    const int t = threadIdx.x, w = t >> 6, lane = t & 63;
    const int row = blockIdx.x * 4 + w;

    ((float2*)xr[w])[lane] = ((const float2*)(z + (size_t)row * DIM))[lane];
    __syncthreads();

    const float4* x4 = (const float4*)xr[w];

    float s1n;
    {
        #pragma clang fp contract(off)
        float r8[8];
        float4 a = x4[0], b = x4[1];
        r8[0] = a.x * a.x; r8[1] = a.y * a.y; r8[2] = a.z * a.z; r8[3] = a.w * a.w;
        r8[4] = b.x * b.x; r8[5] = b.y * b.y; r8[6] = b.z * b.z; r8[7] = b.w * b.w;
        for (int bb = 1; bb < 16; ++bb) {
            float4 c = x4[2 * bb], d = x4[2 * bb + 1];
            r8[0] += c.x * c.x; r8[1] += c.y * c.y; r8[2] += c.z * c.z; r8[3] += c.w * c.w;
            r8[4] += d.x * d.x; r8[5] += d.y * d.y; r8[6] += d.z * d.z; r8[7] += d.w * d.w;
        }
        s1n = ((r8[0] + r8[1]) + (r8[2] + r8[3])) + ((r8[4] + r8[5]) + (r8[6] + r8[7]));
    }

    float bd = FLOATMAX;
    int   bi = 0x7fffffff;

#define EVAL_CODE(code_)                                                      \
    {                                                                         \
        const float4* ep = (const float4*)(embed + (size_t)(code_) * DIM);    \
        float dot = 0.f;                                                      \
        _Pragma("unroll 8")                                                   \
        for (int k4 = 0; k4 < 32; ++k4) {                                     \
            float4 xv = x4[k4], ev = ep[k4];                                  \
            dot = fmaf(xv.x, ev.x, dot);                                      \
            dot = fmaf(xv.y, ev.y, dot);                                      \
            dot = fmaf(xv.z, ev.z, dot);                                      \
            dot = fmaf(xv.w, ev.w, dot);                                      \
        }                                                                     \
        float d = fmaf(-2.0f, dot, s1n);                                      \
        if (d < bd || (d == bd && (code_) < bi)) { bd = d; bi = (code_); }    \
    }

    const unsigned int v = cnt[row];
    const int c0 = (int)(v & 0xffffu);
    const int c1 = (int)(v >> 16);
    const bool ovf0 = (c0 > HCAP), ovf1 = (c1 > HCAP);

    const unsigned int* cl = candg + (size_t)row * 128;

    bool v0 = (!ovf0) && (lane < c0);
    bool v1 = (!ovf1) && (lane < c1);
    unsigned int p0 = v0 ? cl[lane] : 0u;
    unsigned int p1 = v1 ? cl[64 + lane] : 0u;
    int d0 = v0 ? (int)(p0 >> 16) : -1;
    int d1 = v1 ? (int)(p1 >> 16) : -1;

    int m = max(d0, d1);
    #pragma unroll
    for (int o = 32; o >= 1; o >>= 1) m = max(m, __shfl_xor(m, o, 64));

    if (v0 && d0 + DWIN >= m) { int code = (int)(p0 & 0xffffu); EVAL_CODE(code); }
    if (v1 && d1 + DWIN >= m) { int code = (int)(p1 & 0xffffu); EVAL_CODE(code); }

    if (ovf0) {
        for (int j = lane; j < 4096; j += 64) EVAL_CODE(j);
    }
    if (ovf1) {
        for (int j = lane; j < 4096; j += 64) { int code = 4096 + j; EVAL_CODE(code); }
    }
#undef EVAL_CODE

    #pragma unroll
    for (int o = 32; o >= 1; o >>= 1) {
        float d2 = __shfl_xor(bd, o, 64);
        int   i2 = __shfl_xor(bi, o, 64);
        if (d2 < bd || (d2 == bd && i2 < bi)) { bd = d2; bi = i2; }
    }

    float2 zv2 = ((const float2*)xr[w])[lane];
    float2 ev2 = ((const float2*)(embed + (size_t)bi * DIM))[lane];
    float2 o2;
    o2.x = zv2.x + (ev2.x - zv2.x);     // z + (z_q - z), np op order
    o2.y = zv2.y + (ev2.y - zv2.y);
    ((float2*)(out + O_ZQ))[(size_t)row * 64 + lane] = o2;

    float dx = zv2.x - ev2.x, dy = zv2.y - ev2.y;
    float lp = dx * dx + dy * dy;
    #pragma unroll
    for (int off = 32; off >= 1; off >>= 1) lp += __shfl_down(lp, off, 64);

    atomicAdd(&out[O_NSUM + (size_t)bi * DIM + lane * 2],     0.01f * zv2.x);
    atomicAdd(&out[O_NSUM + (size_t)bi * DIM + lane * 2 + 1], 0.01f * zv2.y);
    if (lane == 0) {
        out[O_IDX + row] = (float)bi;
        atomicAdd(&out[O_NSZ + bi], 0.01f);
        lsh[w] = lp;
    }
    __syncthreads();
    if (t == 0)
        atomicAdd(&ws[W_LOSSP + (blockIdx.x & 255)],
                  (lsh[0] + lsh[1]) + (lsh[2] + lsh[3]));
}

// ---------------------------------------------------------------------------
// finalize: n = sum(new_size) -> ws[1]; loss = sum(256 buckets)/(N*D)
// ---------------------------------------------------------------------------
__global__ __launch_bounds__(256)
void vq_finalize(float* __restrict__ out, float* __restrict__ ws) {
    __shared__ float sh[256];
    const int t = threadIdx.x;

    float s = 0.f;
    for (int i = t; i < KC; i += 256) s += out[O_NSZ + i];
    sh[t] = s; __syncthreads();
    for (int o = 128; o > 0; o >>= 1) {
        if (t < o) sh[t] += sh[t + o];
        __syncthreads();
    }
    float n = sh[0];
    __syncthreads();

    sh[t] = ws[W_LOSSP + t]; __syncthreads();
    for (int o = 128; o > 0; o >>= 1) {
        if (t < o) sh[t] += sh[t + o];
        __syncthreads();
    }
    if (t == 0) {
        ws[1] = n;
        out[O_LOSS] = sh[0] / 4194304.0f;
    }
}

__global__ __launch_bounds__(256)
void vq_new_embed(float* __restrict__ out, const float* __restrict__ ws) {
    int i = blockIdx.x * 256 + threadIdx.x;
    if (i >= KC * DIM) return;
    int k = i >> 7;
    float n  = ws[1];
    float ns = out[O_NSZ + k];
    float sm = (ns + 1e-5f) / (n + 0.08192f) * n;
    out[O_NEMB + i] = out[O_NSUM + i] / sm;
}

extern "C" void kernel_launch(void* const* d_in, const int* in_sizes, int n_in,
                              void* d_out, int out_size, void* d_ws, size_t ws_size,
                              hipStream_t stream) {
    const float* z     = (const float*)d_in[0];
    const float* embed = (const float*)d_in[1];
    const float* cs    = (const float*)d_in[2];
    const float* ea    = (const float*)d_in[3];
    float* out = (float*)d_out;
    float* ws  = (float*)d_ws;
    unsigned int* cnt   = (unsigned int*)(ws + W_CNT);
    unsigned int* candg = (unsigned int*)out;          // O_ZQ region (16MB)

    vq_cvt<<<6721, 256, 0, stream>>>(z, embed, cs, ea, out, ws);
    vq_screen<<<512, 512, 0, stream>>>((const uint4*)(ws + W_ZBF),
                                       (const uint4*)(out + O_EBF), cnt, candg);
    vq_rescore_gather<<<NR / 4, 256, 0, stream>>>(z, embed, cnt, candg, out, ws);
    vq_finalize<<<1, 256, 0, stream>>>(out, ws);
    vq_new_embed<<<4096, 256, 0, stream>>>(out, ws);
}

// Round 22
// 186.822 us; speedup vs baseline: 19.0360x; 1.0400x over previous
//
#include <hip/hip_runtime.h>

// VQ-VAE vector quantizer, MI355X. N=32768 rows, D=128, K=8192 codes.
// Round 22 = r19/r21 (best, 194us) with QUAD-epilogue batching in vq_screen:
// four accumulator sets (accQ, fully unrolled static indices), staging and
// barrier cadence per chunk UNCHANGED, cross-lane reduce + export scan once
// per 4 chunks (shfl events halved vs r19). Coarser prefix threshold =>
// HIGHER per-chunk thresholds => FEWER exports (safe direction; superset
// proof unchanged: argmin_dot >= prefix-max - 3.4e-5 > prefix-max - DELTA).
// Rescore/cvt/finalize verbatim r21 (r1/r3-proven numpy-bit-exact chain).

#define KC   8192
#define DIM  128
#define NR   32768

// d_out layout (flat, reference return order, all f32)
#define O_ZQ   0
#define O_LOSS 4194304
#define O_IDX  4194305
#define O_NSZ  4227073
#define O_NSUM 4235265
#define O_NEMB 5283841
// scratch aliases inside d_out (overwritten by later kernels):
#define O_EBF  5283844   // e_bf16 (2MB), inside O_NEMB
// cand32 u32[32768*128] fills O_ZQ exactly; z_q overwrites row-by-row after
// that row's list is consumed (same-wave read-before-write, r10-proven).

// ws layout (f32 index units)
#define W_LOSSP 16       // [16, 272): 256 loss buckets
#define W_CNT   8192     // u32[32768]: lo16 = half0 count, hi16 = half1 count
#define W_ZBF   49152    // z_bf16 (8MB), 16B-aligned
#define HCAP    64

#define DELTA    1.5e-4f   // export guard; >= 4x (2*bf16err + tie-span)
#define DWIN     64        // dot16 filter window (1.22e-4)
#define FLOATMAX 3.402823466e+38f

using short8 = __attribute__((ext_vector_type(8))) short;   // 8 bf16
using f32x4  = __attribute__((ext_vector_type(4))) float;

static __device__ __forceinline__ unsigned int pack2_bf16(float lo, float hi) {
    unsigned int ul = __builtin_bit_cast(unsigned int, lo);
    unsigned int uh = __builtin_bit_cast(unsigned int, hi);
    ul = (ul + 0x7fffu + ((ul >> 16) & 1u)) >> 16;   // RNE to bf16
    uh = (uh + 0x7fffu + ((uh >> 16) & 1u)) >> 16;
    return ul | (uh << 16);
}

// ---------------------------------------------------------------------------
// cvt + init: z->bf16 (ws), embed->bf16, seed new_size/new_sum, zero cnt
// and loss buckets.
// ---------------------------------------------------------------------------
__global__ __launch_bounds__(256)
void vq_cvt(const float* __restrict__ z, const float* __restrict__ embed,
            const float* __restrict__ cs, const float* __restrict__ ea,
            float* __restrict__ out, float* __restrict__ ws) {
    int gid = blockIdx.x * 256 + threadIdx.x;
    if (gid < 524288) {
        const float4* s = (const float4*)z + (size_t)gid * 2;
        float4 a = s[0], b = s[1];
        uint4 wv;
        wv.x = pack2_bf16(a.x, a.y); wv.y = pack2_bf16(a.z, a.w);
        wv.z = pack2_bf16(b.x, b.y); wv.w = pack2_bf16(b.z, b.w);
        ((uint4*)(ws + W_ZBF))[gid] = wv;
    } else if (gid < 655360) {
        int j = gid - 524288;
        const float4* s = (const float4*)embed + (size_t)j * 2;
        float4 a = s[0], b = s[1];
        uint4 wv;
        wv.x = pack2_bf16(a.x, a.y); wv.y = pack2_bf16(a.z, a.w);
        wv.z = pack2_bf16(b.x, b.y); wv.w = pack2_bf16(b.z, b.w);
        ((uint4*)(out + O_EBF))[j] = wv;
    } else if (gid < 1703936) {
        int j = gid - 655360;
        out[O_NSUM + j] = 0.99f * ea[j];
    } else if (gid < 1712128) {
        int j = gid - 1703936;
        out[O_NSZ + j] = 0.99f * cs[j];
    } else if (gid < 1720320) {
        int j = gid - 1712128;
        ((uint4*)(ws + W_CNT))[j] = make_uint4(0u, 0u, 0u, 0u);
    } else if (gid < 1720576) {
        ws[W_LOSSP + (gid - 1720320)] = 0.f;
    }
}

// ---------------------------------------------------------------------------
// Screen (r5/r18 structure + quad epilogue). Grid 512: block = (rb = bid>>1,
// cb = bid&1) -> 128 rows x 4096 codes, 64 chunks of 64 codes processed in
// 16 quads. 8 waves: chf = w&1, rh = w>>1 (32-row quarter), 2mf x 2nf tiles.
// Ring-4 LDS via global_load_lds (pre-swizzled source, wave-uniform dest),
// prefetch-2, counted vmcnt, one s_barrier per chunk (cadence unchanged).
// Cross-lane reduce + export scan once per QUAD. Private runmax stripes.
// ---------------------------------------------------------------------------
__global__ __launch_bounds__(512, 4)
void vq_screen(const uint4* __restrict__ zb4, const uint4* __restrict__ eb4,
               unsigned int* __restrict__ cnt, unsigned int* __restrict__ candg) {
    __shared__ uint4 els[4 * 1024];          // 4 x 16 KiB ring
    __shared__ unsigned int cnt_l[128];      // per-row export counters

    const int t    = threadIdx.x;
    const int lane = t & 63;
    const int w    = __builtin_amdgcn_readfirstlane(t >> 6);   // 0..7
    const int g    = lane >> 4;     // 0..3
    const int q    = lane & 15;     // 0..15
    const int chf  = w & 1;
    const int rh   = w >> 1;        // 0..3
    const int rb   = blockIdx.x >> 1;
    const int cb   = blockIdx.x & 1;
    const int row0 = rb * 128;

    if (t < 128) cnt_l[t] = 0u;

    // staging source (pre-swizzled: LDS slot (c,s) holds granule s^(c&7))
    const uint4* gsrc[2];
    #pragma unroll
    for (int i = 0; i < 2; ++i) {
        int c = w * 8 + i * 4 + g;                       // code-in-chunk 0..63
        gsrc[i] = eb4 + (size_t)cb * 65536 + c * 16 + (q ^ (c & 7));
    }

#define STAGE(CH)                                                             \
    {                                                                         \
        _Pragma("unroll")                                                     \
        for (int i = 0; i < 2; ++i)                                           \
            __builtin_amdgcn_global_load_lds(                                 \
                (const __attribute__((address_space(1))) unsigned int*)       \
                    (gsrc[i] + (size_t)(CH) * 1024),                          \
                (__attribute__((address_space(3))) unsigned int*)             \
                    &els[((CH) & 3) * 1024 + w * 128 + i * 64],               \
                16, 0, 0);                                                    \
    }

#define SUBITER(CHI, ACC)                                                     \
    {                                                                         \
        if ((CHI) <= 61) {                                                    \
            STAGE((CHI) + 2);                                                 \
            asm volatile("s_waitcnt vmcnt(4)" ::: "memory");                  \
        } else if ((CHI) == 62) {                                             \
            asm volatile("s_waitcnt vmcnt(2)" ::: "memory");                  \
        } else {                                                              \
            asm volatile("s_waitcnt vmcnt(0)" ::: "memory");                  \
        }                                                                     \
        __builtin_amdgcn_s_barrier();                                         \
        {                                                                     \
            const uint4* el = els + ((CHI) & 3) * 1024;                       \
            _Pragma("unroll")                                                 \
            for (int ks = 0; ks < 4; ++ks) {                                  \
                int k8 = ks * 4 + g;                                          \
                short8 af[2];                                                 \
                _Pragma("unroll")                                             \
                for (int mf = 0; mf < 2; ++mf) {                              \
                    int cm = chf * 32 + mf * 16 + q;                          \
                    af[mf] = __builtin_bit_cast(short8,                       \
                                 el[cm * 16 + (k8 ^ (cm & 7))]);              \
                }                                                             \
                _Pragma("unroll")                                             \
                for (int mf = 0; mf < 2; ++mf)                                \
                    _Pragma("unroll")                                         \
                    for (int nf = 0; nf < 2; ++nf)                            \
                        ACC[mf][nf] =                                         \
                            __builtin_amdgcn_mfma_f32_16x16x32_bf16(          \
                                af[mf], bx[nf][ks], ACC[mf][nf], 0, 0, 0);    \
            }                                                                 \
        }                                                                     \
    }

    float runmax[2] = { -FLOATMAX, -FLOATMAX };

    STAGE(0);
    STAGE(1);

    // x B-frags (chunk-invariant)
    short8 bx[2][4];
    #pragma unroll
    for (int nf = 0; nf < 2; ++nf) {
        const uint4* zp = zb4 + (size_t)(row0 + rh * 32 + nf * 16 + q) * 16;
        #pragma unroll
        for (int ks = 0; ks < 4; ++ks)
            bx[nf][ks] = __builtin_bit_cast(short8, zp[ks * 4 + g]);
    }

    for (int ch = 0; ch < 64; ch += 4) {
        f32x4 accQ[4][2][2];
        #pragma unroll
        for (int s = 0; s < 4; ++s)
            #pragma unroll
            for (int mf = 0; mf < 2; ++mf)
                #pragma unroll
                for (int nf = 0; nf < 2; ++nf) accQ[s][mf][nf] = (f32x4)0.f;

        SUBITER(ch + 0, accQ[0]);
        SUBITER(ch + 1, accQ[1]);
        SUBITER(ch + 2, accQ[2]);
        SUBITER(ch + 3, accQ[3]);

        // ---- quad epilogue: reduce + guarded export over all 4 chunks ----
        #pragma unroll
        for (int nf = 0; nf < 2; ++nf) {
            float cm = -FLOATMAX;
            #pragma unroll
            for (int s = 0; s < 4; ++s)
                #pragma unroll
                for (int mf = 0; mf < 2; ++mf)
                    #pragma unroll
                    for (int rg = 0; rg < 4; ++rg)
                        cm = fmaxf(cm, accQ[s][mf][nf][rg]);
            cm = fmaxf(cm, __shfl_xor(cm, 16, 64));
            cm = fmaxf(cm, __shfl_xor(cm, 32, 64));

            bool scan = (cm + DELTA > runmax[nf]);
            runmax[nf] = fmaxf(runmax[nf], cm);
            if (scan) {
                float thr = runmax[nf] - DELTA;
                int r_l = rh * 32 + nf * 16 + q;
                #pragma unroll
                for (int s = 0; s < 4; ++s)
                    #pragma unroll
                    for (int mf = 0; mf < 2; ++mf)
                        #pragma unroll
                        for (int rg = 0; rg < 4; ++rg) {
                            if (accQ[s][mf][nf][rg] > thr) {
                                int code = cb * 4096 + (ch + s) * 64
                                         + chf * 32 + mf * 16 + g * 4 + rg;
                                unsigned int dot16 = (unsigned int)(int)
                                    fmaf(accQ[s][mf][nf][rg], 524288.0f,
                                         32768.0f);
                                unsigned int slot = atomicAdd(&cnt_l[r_l], 1u);
                                if (slot < HCAP)
                                    candg[(size_t)(row0 + r_l) * 128
                                          + cb * 64 + slot]
                                        = (unsigned int)code | (dot16 << 16);
                            }
                        }
            }
        }
    }
#undef SUBITER
#undef STAGE

    __syncthreads();
    if (t < 128) {
        unsigned int v = min(cnt_l[t], (unsigned int)(HCAP + 1));
        atomicAdd(&cnt[row0 + t], v << (16 * cb));
    }
}

// ---------------------------------------------------------------------------
// Merged phase 2 (r10/r18-proven): dot16 DWIN filter -> exact rescore
// (numpy-bit-exact, r1/r3-proven) of survivors -> idx, z_q, loss partial,
// EMA stats. Overflowed half -> exact scan of its 4096 codes.
// ---------------------------------------------------------------------------
__global__ __launch_bounds__(256)
void vq_rescore_gather(const float* __restrict__ z,
                       const float* __restrict__ embed,
                       const unsigned int* __restrict__ cnt,
                       const unsigned int* __restrict__ candg,
                       float* __restrict__ out, float* __restrict__ ws) {
    __shared__ float xr[4][128];
    __shared__ float lsh[4];
    const int t = threadIdx.x, w = t >> 6, lane = t & 63;
    const int row = blockIdx.x * 4 + w;

    ((float2*)xr[w])[lane] = ((const float2*)(z + (size_t)row * DIM))[lane];
    __syncthreads();

    const float4* x4 = (const float4*)xr[w];

    float s1n;
    {
        #pragma clang fp contract(off)
        float r8[8];
        float4 a = x4[0], b = x4[1];
        r8[0] = a.x * a.x; r8[1] = a.y * a.y; r8[2] = a.z * a.z; r8[3] = a.w * a.w;
        r8[4] = b.x * b.x; r8[5] = b.y * b.y; r8[6] = b.z * b.z; r8[7] = b.w * b.w;
        for (int bb = 1; bb < 16; ++bb) {
            float4 c = x4[2 * bb], d = x4[2 * bb + 1];
            r8[0] += c.x * c.x; r8[1] += c.y * c.y; r8[2] += c.z * c.z; r8[3] += c.w * c.w;
            r8[4] += d.x * d.x; r8[5] += d.y * d.y; r8[6] += d.z * d.z; r8[7] += d.w * d.w;
        }
        s1n = ((r8[0] + r8[1]) + (r8[2] + r8[3])) + ((r8[4] + r8[5]) + (r8[6] + r8[7]));
    }

    float bd = FLOATMAX;
    int   bi = 0x7fffffff;

#define EVAL_CODE(code_)                                                      \
    {                                                                         \
        const float4* ep = (const float4*)(embed + (size_t)(code_) * DIM);    \
        float dot = 0.f;                                                      \
        _Pragma("unroll 8")                                                   \
        for (int k4 = 0; k4 < 32; ++k4) {                                     \
            float4 xv = x4[k4], ev = ep[k4];                                  \
            dot = fmaf(xv.x, ev.x, dot);                                      \
            dot = fmaf(xv.y, ev.y, dot);                                      \
            dot = fmaf(xv.z, ev.z, dot);                                      \
            dot = fmaf(xv.w, ev.w, dot);                                      \
        }                                                                     \
        float d = fmaf(-2.0f, dot, s1n);                                      \
        if (d < bd || (d == bd && (code_) < bi)) { bd = d; bi = (code_); }    \
    }

    const unsigned int v = cnt[row];
    const int c0 = (int)(v & 0xffffu);
    const int c1 = (int)(v >> 16);
    const bool ovf0 = (c0 > HCAP), ovf1 = (c1 > HCAP);

    const unsigned int* cl = candg + (size_t)row * 128;

    bool v0 = (!ovf0) && (lane < c0);
    bool v1 = (!ovf1) && (lane < c1);
    unsigned int p0 = v0 ? cl[lane] : 0u;
    unsigned int p1 = v1 ? cl[64 + lane] : 0u;
    int d0 = v0 ? (int)(p0 >> 16) : -1;
    int d1 = v1 ? (int)(p1 >> 16) : -1;

    int m = max(d0, d1);
    #pragma unroll
    for (int o = 32; o >= 1; o >>= 1) m = max(m, __shfl_xor(m, o, 64));

    if (v0 && d0 + DWIN >= m) { int code = (int)(p0 & 0xffffu); EVAL_CODE(code); }
    if (v1 && d1 + DWIN >= m) { int code = (int)(p1 & 0xffffu); EVAL_CODE(code); }

    if (ovf0) {
        for (int j = lane; j < 4096; j += 64) EVAL_CODE(j);
    }
    if (ovf1) {
        for (int j = lane; j < 4096; j += 64) { int code = 4096 + j; EVAL_CODE(code); }
    }
#undef EVAL_CODE

    #pragma unroll
    for (int o = 32; o >= 1; o >>= 1) {
        float d2 = __shfl_xor(bd, o, 64);
        int   i2 = __shfl_xor(bi, o, 64);
        if (d2 < bd || (d2 == bd && i2 < bi)) { bd = d2; bi = i2; }
    }

    float2 zv2 = ((const float2*)xr[w])[lane];
    float2 ev2 = ((const float2*)(embed + (size_t)bi * DIM))[lane];
    float2 o2;
    o2.x = zv2.x + (ev2.x - zv2.x);     // z + (z_q - z), np op order
    o2.y = zv2.y + (ev2.y - zv2.y);
    ((float2*)(out + O_ZQ))[(size_t)row * 64 + lane] = o2;

    float dx = zv2.x - ev2.x, dy = zv2.y - ev2.y;
    float lp = dx * dx + dy * dy;
    #pragma unroll
    for (int off = 32; off >= 1; off >>= 1) lp += __shfl_down(lp, off, 64);

    atomicAdd(&out[O_NSUM + (size_t)bi * DIM + lane * 2],     0.01f * zv2.x);
    atomicAdd(&out[O_NSUM + (size_t)bi * DIM + lane * 2 + 1], 0.01f * zv2.y);
    if (lane == 0) {
        out[O_IDX + row] = (float)bi;
        atomicAdd(&out[O_NSZ + bi], 0.01f);
        lsh[w] = lp;
    }
    __syncthreads();
    if (t == 0)
        atomicAdd(&ws[W_LOSSP + (blockIdx.x & 255)],
                  (lsh[0] + lsh[1]) + (lsh[2] + lsh[3]));
}

// ---------------------------------------------------------------------------
// finalize: n = sum(new_size) -> ws[1]; loss = sum(256 buckets)/(N*D)
// ---------------------------------------------------------------------------
__global__ __launch_bounds__(256)
void vq_finalize(float* __restrict__ out, float* __restrict__ ws) {
    __shared__ float sh[256];
    const int t = threadIdx.x;

    float s = 0.f;
    for (int i = t; i < KC; i += 256) s += out[O_NSZ + i];
    sh[t] = s; __syncthreads();
    for (int o = 128; o > 0; o >>= 1) {
        if (t < o) sh[t] += sh[t + o];
        __syncthreads();
    }
    float n = sh[0];
    __syncthreads();

    sh[t] = ws[W_LOSSP + t]; __syncthreads();
    for (int o = 128; o > 0; o >>= 1) {
        if (t < o) sh[t] += sh[t + o];
        __syncthreads();
    }
    if (t == 0) {
        ws[1] = n;
        out[O_LOSS] = sh[0] / 4194304.0f;
    }
}

__global__ __launch_bounds__(256)
void vq_new_embed(float* __restrict__ out, const float* __restrict__ ws) {
    int i = blockIdx.x * 256 + threadIdx.x;
    if (i >= KC * DIM) return;
    int k = i >> 7;
    float n  = ws[1];
    float ns = out[O_NSZ + k];
    float sm = (ns + 1e-5f) / (n + 0.08192f) * n;
    out[O_NEMB + i] = out[O_NSUM + i] / sm;
}

extern "C" void kernel_launch(void* const* d_in, const int* in_sizes, int n_in,
                              void* d_out, int out_size, void* d_ws, size_t ws_size,
                              hipStream_t stream) {
    const float* z     = (const float*)d_in[0];
    const float* embed = (const float*)d_in[1];
    const float* cs    = (const float*)d_in[2];
    const float* ea    = (const float*)d_in[3];
    float* out = (float*)d_out;
    float* ws  = (float*)d_ws;
    unsigned int* cnt   = (unsigned int*)(ws + W_CNT);
    unsigned int* candg = (unsigned int*)out;          // O_ZQ region (16MB)

    vq_cvt<<<6721, 256, 0, stream>>>(z, embed, cs, ea, out, ws);
    vq_screen<<<512, 512, 0, stream>>>((const uint4*)(ws + W_ZBF),
                                       (const uint4*)(out + O_EBF), cnt, candg);
    vq_rescore_gather<<<NR / 4, 256, 0, stream>>>(z, embed, cnt, candg, out, ws);
    vq_finalize<<<1, 256, 0, stream>>>(out, ws);
    vq_new_embed<<<4096, 256, 0, stream>>>(out, ws);
}

// Round 23
// 176.908 us; speedup vs baseline: 20.1027x; 1.0560x over previous
//
#include <hip/hip_runtime.h>

// VQ-VAE vector quantizer, MI355X. N=32768 rows, D=128, K=8192 codes.
// Round 23 = r22 (best, 186.8us) with the vq_finalize launch eliminated:
//  - n = 0.99*sum(cs) + 0.01*32768; sum(cs) computed in vq_cvt (its cs range
//    spans exactly 32 aligned blocks -> block-reduce into 32 unconditional
//    ws partial slots, no zeroing needed). n only feeds Laplace smoothing;
//    reorder-level FP diff (thresholds passed with ~5000x margin all session).
//  - loss (256 buckets) reduced by vq_new_embed block 0.
// Screen (quad-epilogue) and rescore verbatim r22 (r1/r3-proven numerics).

#define KC   8192
#define DIM  128
#define NR   32768

// d_out layout (flat, reference return order, all f32)
#define O_ZQ   0
#define O_LOSS 4194304
#define O_IDX  4194305
#define O_NSZ  4227073
#define O_NSUM 4235265
#define O_NEMB 5283841
// scratch aliases inside d_out (overwritten by later kernels):
#define O_EBF  5283844   // e_bf16 (2MB), inside O_NEMB
// cand32 u32[32768*128] fills O_ZQ exactly; z_q overwrites row-by-row after
// that row's list is consumed (same-wave read-before-write, r10-proven).

// ws layout (f32 index units)
#define W_LOSSP 16       // [16, 272): 256 loss buckets
#define W_CSP   280      // [280, 312): 32 cs-sum partials (written each call)
#define W_CNT   8192     // u32[32768]: lo16 = half0 count, hi16 = half1 count
#define W_ZBF   49152    // z_bf16 (8MB), 16B-aligned
#define HCAP    64

#define DELTA    1.5e-4f   // export guard; >= 4x (2*bf16err + tie-span)
#define DWIN     64        // dot16 filter window (1.22e-4)
#define FLOATMAX 3.402823466e+38f

using short8 = __attribute__((ext_vector_type(8))) short;   // 8 bf16
using f32x4  = __attribute__((ext_vector_type(4))) float;

static __device__ __forceinline__ unsigned int pack2_bf16(float lo, float hi) {
    unsigned int ul = __builtin_bit_cast(unsigned int, lo);
    unsigned int uh = __builtin_bit_cast(unsigned int, hi);
    ul = (ul + 0x7fffu + ((ul >> 16) & 1u)) >> 16;   // RNE to bf16
    uh = (uh + 0x7fffu + ((uh >> 16) & 1u)) >> 16;
    return ul | (uh << 16);
}

// ---------------------------------------------------------------------------
// cvt + init: z->bf16 (ws), embed->bf16, seed new_size/new_sum, zero cnt
// and loss buckets, 32 cs-sum partials. All branch ranges are 256-aligned
// -> per-block uniform branches (syncthreads-safe).
// ---------------------------------------------------------------------------
__global__ __launch_bounds__(256)
void vq_cvt(const float* __restrict__ z, const float* __restrict__ embed,
            const float* __restrict__ cs, const float* __restrict__ ea,
            float* __restrict__ out, float* __restrict__ ws) {
    __shared__ float sred[256];
    int gid = blockIdx.x * 256 + threadIdx.x;
    if (gid < 524288) {
        const float4* s = (const float4*)z + (size_t)gid * 2;
        float4 a = s[0], b = s[1];
        uint4 wv;
        wv.x = pack2_bf16(a.x, a.y); wv.y = pack2_bf16(a.z, a.w);
        wv.z = pack2_bf16(b.x, b.y); wv.w = pack2_bf16(b.z, b.w);
        ((uint4*)(ws + W_ZBF))[gid] = wv;
    } else if (gid < 655360) {
        int j = gid - 524288;
        const float4* s = (const float4*)embed + (size_t)j * 2;
        float4 a = s[0], b = s[1];
        uint4 wv;
        wv.x = pack2_bf16(a.x, a.y); wv.y = pack2_bf16(a.z, a.w);
        wv.z = pack2_bf16(b.x, b.y); wv.w = pack2_bf16(b.z, b.w);
        ((uint4*)(out + O_EBF))[j] = wv;
    } else if (gid < 1703936) {
        int j = gid - 655360;
        out[O_NSUM + j] = 0.99f * ea[j];
    } else if (gid < 1712128) {
        int j = gid - 1703936;
        float c = cs[j];
        out[O_NSZ + j] = 0.99f * c;
        // 32 blocks cover this range exactly: block-reduce cs -> partial
        sred[threadIdx.x] = c;
        __syncthreads();
        for (int o = 128; o > 0; o >>= 1) {
            if (threadIdx.x < o) sred[threadIdx.x] += sred[threadIdx.x + o];
            __syncthreads();
        }
        if (threadIdx.x == 0) ws[W_CSP + (blockIdx.x - 6656)] = sred[0];
    } else if (gid < 1720320) {
        int j = gid - 1712128;
        ((uint4*)(ws + W_CNT))[j] = make_uint4(0u, 0u, 0u, 0u);
    } else if (gid < 1720576) {
        ws[W_LOSSP + (gid - 1720320)] = 0.f;
    }
}

// ---------------------------------------------------------------------------
// Screen (r22 verbatim: r5/r18 structure + quad epilogue). Grid 512: block =
// (rb = bid>>1, cb = bid&1) -> 128 rows x 4096 codes, 64 chunks of 64 codes
// in 16 quads. 8 waves: chf = w&1, rh = w>>1, 2mf x 2nf tiles. Ring-4 LDS
// via global_load_lds (pre-swizzled source, wave-uniform dest), prefetch-2,
// counted vmcnt, one s_barrier per chunk. Reduce + export once per QUAD.
// ---------------------------------------------------------------------------
__global__ __launch_bounds__(512, 4)
void vq_screen(const uint4* __restrict__ zb4, const uint4* __restrict__ eb4,
               unsigned int* __restrict__ cnt, unsigned int* __restrict__ candg) {
    __shared__ uint4 els[4 * 1024];          // 4 x 16 KiB ring
    __shared__ unsigned int cnt_l[128];      // per-row export counters

    const int t    = threadIdx.x;
    const int lane = t & 63;
    const int w    = __builtin_amdgcn_readfirstlane(t >> 6);   // 0..7
    const int g    = lane >> 4;     // 0..3
    const int q    = lane & 15;     // 0..15
    const int chf  = w & 1;
    const int rh   = w >> 1;        // 0..3
    const int rb   = blockIdx.x >> 1;
    const int cb   = blockIdx.x & 1;
    const int row0 = rb * 128;

    if (t < 128) cnt_l[t] = 0u;

    // staging source (pre-swizzled: LDS slot (c,s) holds granule s^(c&7))
    const uint4* gsrc[2];
    #pragma unroll
    for (int i = 0; i < 2; ++i) {
        int c = w * 8 + i * 4 + g;                       // code-in-chunk 0..63
        gsrc[i] = eb4 + (size_t)cb * 65536 + c * 16 + (q ^ (c & 7));
    }

#define STAGE(CH)                                                             \
    {                                                                         \
        _Pragma("unroll")                                                     \
        for (int i = 0; i < 2; ++i)                                           \
            __builtin_amdgcn_global_load_lds(                                 \
                (const __attribute__((address_space(1))) unsigned int*)       \
                    (gsrc[i] + (size_t)(CH) * 1024),                          \
                (__attribute__((address_space(3))) unsigned int*)             \
                    &els[((CH) & 3) * 1024 + w * 128 + i * 64],               \
                16, 0, 0);                                                    \
    }

#define SUBITER(CHI, ACC)                                                     \
    {                                                                         \
        if ((CHI) <= 61) {                                                    \
            STAGE((CHI) + 2);                                                 \
            asm volatile("s_waitcnt vmcnt(4)" ::: "memory");                  \
        } else if ((CHI) == 62) {                                             \
            asm volatile("s_waitcnt vmcnt(2)" ::: "memory");                  \
        } else {                                                              \
            asm volatile("s_waitcnt vmcnt(0)" ::: "memory");                  \
        }                                                                     \
        __builtin_amdgcn_s_barrier();                                         \
        {                                                                     \
            const uint4* el = els + ((CHI) & 3) * 1024;                       \
            _Pragma("unroll")                                                 \
            for (int ks = 0; ks < 4; ++ks) {                                  \
                int k8 = ks * 4 + g;                                          \
                short8 af[2];                                                 \
                _Pragma("unroll")                                             \
                for (int mf = 0; mf < 2; ++mf) {                              \
                    int cm = chf * 32 + mf * 16 + q;                          \
                    af[mf] = __builtin_bit_cast(short8,                       \
                                 el[cm * 16 + (k8 ^ (cm & 7))]);              \
                }                                                             \
                _Pragma("unroll")                                             \
                for (int mf = 0; mf < 2; ++mf)                                \
                    _Pragma("unroll")                                         \
                    for (int nf = 0; nf < 2; ++nf)                            \
                        ACC[mf][nf] =                                         \
                            __builtin_amdgcn_mfma_f32_16x16x32_bf16(          \
                                af[mf], bx[nf][ks], ACC[mf][nf], 0, 0, 0);    \
            }                                                                 \
        }                                                                     \
    }

    float runmax[2] = { -FLOATMAX, -FLOATMAX };

    STAGE(0);
    STAGE(1);

    // x B-frags (chunk-invariant)
    short8 bx[2][4];
    #pragma unroll
    for (int nf = 0; nf < 2; ++nf) {
        const uint4* zp = zb4 + (size_t)(row0 + rh * 32 + nf * 16 + q) * 16;
        #pragma unroll
        for (int ks = 0; ks < 4; ++ks)
            bx[nf][ks] = __builtin_bit_cast(short8, zp[ks * 4 + g]);
    }

    for (int ch = 0; ch < 64; ch += 4) {
        f32x4 accQ[4][2][2];
        #pragma unroll
        for (int s = 0; s < 4; ++s)
            #pragma unroll
            for (int mf = 0; mf < 2; ++mf)
                #pragma unroll
                for (int nf = 0; nf < 2; ++nf) accQ[s][mf][nf] = (f32x4)0.f;

        SUBITER(ch + 0, accQ[0]);
        SUBITER(ch + 1, accQ[1]);
        SUBITER(ch + 2, accQ[2]);
        SUBITER(ch + 3, accQ[3]);

        // ---- quad epilogue: reduce + guarded export over all 4 chunks ----
        #pragma unroll
        for (int nf = 0; nf < 2; ++nf) {
            float cm = -FLOATMAX;
            #pragma unroll
            for (int s = 0; s < 4; ++s)
                #pragma unroll
                for (int mf = 0; mf < 2; ++mf)
                    #pragma unroll
                    for (int rg = 0; rg < 4; ++rg)
                        cm = fmaxf(cm, accQ[s][mf][nf][rg]);
            cm = fmaxf(cm, __shfl_xor(cm, 16, 64));
            cm = fmaxf(cm, __shfl_xor(cm, 32, 64));

            bool scan = (cm + DELTA > runmax[nf]);
            runmax[nf] = fmaxf(runmax[nf], cm);
            if (scan) {
                float thr = runmax[nf] - DELTA;
                int r_l = rh * 32 + nf * 16 + q;
                #pragma unroll
                for (int s = 0; s < 4; ++s)
                    #pragma unroll
                    for (int mf = 0; mf < 2; ++mf)
                        #pragma unroll
                        for (int rg = 0; rg < 4; ++rg) {
                            if (accQ[s][mf][nf][rg] > thr) {
                                int code = cb * 4096 + (ch + s) * 64
                                         + chf * 32 + mf * 16 + g * 4 + rg;
                                unsigned int dot16 = (unsigned int)(int)
                                    fmaf(accQ[s][mf][nf][rg], 524288.0f,
                                         32768.0f);
                                unsigned int slot = atomicAdd(&cnt_l[r_l], 1u);
                                if (slot < HCAP)
                                    candg[(size_t)(row0 + r_l) * 128
                                          + cb * 64 + slot]
                                        = (unsigned int)code | (dot16 << 16);
                            }
                        }
            }
        }
    }
#undef SUBITER
#undef STAGE

    __syncthreads();
    if (t < 128) {
        unsigned int v = min(cnt_l[t], (unsigned int)(HCAP + 1));
        atomicAdd(&cnt[row0 + t], v << (16 * cb));
    }
}

// ---------------------------------------------------------------------------
// Merged phase 2 (r10/r18-proven): dot16 DWIN filter -> exact rescore
// (numpy-bit-exact, r1/r3-proven) of survivors -> idx, z_q, loss partial,
// EMA stats. Overflowed half -> exact scan of its 4096 codes.
// ---------------------------------------------------------------------------
__global__ __launch_bounds__(256)
void vq_rescore_gather(const float* __restrict__ z,
                       const float* __restrict__ embed,
                       const unsigned int* __restrict__ cnt,
                       const unsigned int* __restrict__ candg,
                       float* __restrict__ out, float* __restrict__ ws) {
    __shared__ float xr[4][128];
    __shared__ float lsh[4];
    const int t = threadIdx.x, w = t >> 6, lane = t & 63;
    const int row = blockIdx.x * 4 + w;

    ((float2*)xr[w])[lane] = ((const float2*)(z + (size_t)row * DIM))[lane];
    __syncthreads();

    const float4* x4 = (const float4*)xr[w];

    float s1n;
    {
        #pragma clang fp contract(off)
        float r8[8];
        float4 a = x4[0], b = x4[1];
        r8[0] = a.x * a.x; r8[1] = a.y * a.y; r8[2] = a.z * a.z; r8[3] = a.w * a.w;
        r8[4] = b.x * b.x; r8[5] = b.y * b.y; r8[6] = b.z * b.z; r8[7] = b.w * b.w;
        for (int bb = 1; bb < 16; ++bb) {
            float4 c = x4[2 * bb], d = x4[2 * bb + 1];
            r8[0] += c.x * c.x; r8[1] += c.y * c.y; r8[2] += c.z * c.z; r8[3] += c.w * c.w;
            r8[4] += d.x * d.x; r8[5] += d.y * d.y; r8[6] += d.z * d.z; r8[7] += d.w * d.w;
        }
        s1n = ((r8[0] + r8[1]) + (r8[2] + r8[3])) + ((r8[4] + r8[5]) + (r8[6] + r8[7]));
    }

    float bd = FLOATMAX;
    int   bi = 0x7fffffff;

#define EVAL_CODE(code_)                                                      \
    {                                                                         \
        const float4* ep = (const float4*)(embed + (size_t)(code_) * DIM);    \
        float dot = 0.f;                                                      \
        _Pragma("unroll 8")                                                   \
        for (int k4 = 0; k4 < 32; ++k4) {                                     \
            float4 xv = x4[k4], ev = ep[k4];                                  \
            dot = fmaf(xv.x, ev.x, dot);                                      \
            dot = fmaf(xv.y, ev.y, dot);                                      \
            dot = fmaf(xv.z, ev.z, dot);                                      \
            dot = fmaf(xv.w, ev.w, dot);                                      \
        }                                                                     \
        float d = fmaf(-2.0f, dot, s1n);                                      \
        if (d < bd || (d == bd && (code_) < bi)) { bd = d; bi = (code_); }    \
    }

    const unsigned int v = cnt[row];
    const int c0 = (int)(v & 0xffffu);
    const int c1 = (int)(v >> 16);
    const bool ovf0 = (c0 > HCAP), ovf1 = (c1 > HCAP);

    const unsigned int* cl = candg + (size_t)row * 128;

    bool v0 = (!ovf0) && (lane < c0);
    bool v1 = (!ovf1) && (lane < c1);
    unsigned int p0 = v0 ? cl[lane] : 0u;
    unsigned int p1 = v1 ? cl[64 + lane] : 0u;
    int d0 = v0 ? (int)(p0 >> 16) : -1;
    int d1 = v1 ? (int)(p1 >> 16) : -1;

    int m = max(d0, d1);
    #pragma unroll
    for (int o = 32; o >= 1; o >>= 1) m = max(m, __shfl_xor(m, o, 64));

    if (v0 && d0 + DWIN >= m) { int code = (int)(p0 & 0xffffu); EVAL_CODE(code); }
    if (v1 && d1 + DWIN >= m) { int code = (int)(p1 & 0xffffu); EVAL_CODE(code); }

    if (ovf0) {
        for (int j = lane; j < 4096; j += 64) EVAL_CODE(j);
    }
    if (ovf1) {
        for (int j = lane; j < 4096; j += 64) { int code = 4096 + j; EVAL_CODE(code); }
    }
#undef EVAL_CODE

    #pragma unroll
    for (int o = 32; o >= 1; o >>= 1) {
        float d2 = __shfl_xor(bd, o, 64);
        int   i2 = __shfl_xor(bi, o, 64);
        if (d2 < bd || (d2 == bd && i2 < bi)) { bd = d2; bi = i2; }
    }

    float2 zv2 = ((const float2*)xr[w])[lane];
    float2 ev2 = ((const float2*)(embed + (size_t)bi * DIM))[lane];
    float2 o2;
    o2.x = zv2.x + (ev2.x - zv2.x);     // z + (z_q - z), np op order
    o2.y = zv2.y + (ev2.y - zv2.y);
    ((float2*)(out + O_ZQ))[(size_t)row * 64 + lane] = o2;

    float dx = zv2.x - ev2.x, dy = zv2.y - ev2.y;
    float lp = dx * dx + dy * dy;
    #pragma unroll
    for (int off = 32; off >= 1; off >>= 1) lp += __shfl_down(lp, off, 64);

    atomicAdd(&out[O_NSUM + (size_t)bi * DIM + lane * 2],     0.01f * zv2.x);
    atomicAdd(&out[O_NSUM + (size_t)bi * DIM + lane * 2 + 1], 0.01f * zv2.y);
    if (lane == 0) {
        out[O_IDX + row] = (float)bi;
        atomicAdd(&out[O_NSZ + bi], 0.01f);
        lsh[w] = lp;
    }
    __syncthreads();
    if (t == 0)
        atomicAdd(&ws[W_LOSSP + (blockIdx.x & 255)],
                  (lsh[0] + lsh[1]) + (lsh[2] + lsh[3]));
}

// ---------------------------------------------------------------------------
// new_embed (+ fused loss): n = 0.99*sum(cs partials) + 0.01*32768;
// new_embed = new_sum / ((new_size + eps)/(n + K*eps) * n).
// Block 0 additionally reduces the 256 loss buckets -> out[O_LOSS].
// ---------------------------------------------------------------------------
__global__ __launch_bounds__(256)
void vq_new_embed(float* __restrict__ out, const float* __restrict__ ws) {
    __shared__ float sh[256];
    const int t = threadIdx.x;

    float scs = 0.f;
    #pragma unroll
    for (int i = 0; i < 32; ++i) scs += ws[W_CSP + i];
    const float n = fmaf(0.99f, scs, 327.68f);   // + 0.01*32768

    int i = blockIdx.x * 256 + t;
    if (i < KC * DIM) {
        int k = i >> 7;
        float ns = out[O_NSZ + k];
        float sm = (ns + 1e-5f) / (n + 0.08192f) * n;
        out[O_NEMB + i] = out[O_NSUM + i] / sm;
    }

    if (blockIdx.x == 0) {
        sh[t] = ws[W_LOSSP + t]; __syncthreads();
        for (int o = 128; o > 0; o >>= 1) {
            if (t < o) sh[t] += sh[t + o];
            __syncthreads();
        }
        if (t == 0) out[O_LOSS] = sh[0] / 4194304.0f;
    }
}

extern "C" void kernel_launch(void* const* d_in, const int* in_sizes, int n_in,
                              void* d_out, int out_size, void* d_ws, size_t ws_size,
                              hipStream_t stream) {
    const float* z     = (const float*)d_in[0];
    const float* embed = (const float*)d_in[1];
    const float* cs    = (const float*)d_in[2];
    const float* ea    = (const float*)d_in[3];
    float* out = (float*)d_out;
    float* ws  = (float*)d_ws;
    unsigned int* cnt   = (unsigned int*)(ws + W_CNT);
    unsigned int* candg = (unsigned int*)out;          // O_ZQ region (16MB)

    vq_cvt<<<6721, 256, 0, stream>>>(z, embed, cs, ea, out, ws);
    vq_screen<<<512, 512, 0, stream>>>((const uint4*)(ws + W_ZBF),
                                       (const uint4*)(out + O_EBF), cnt, candg);
    vq_rescore_gather<<<NR / 4, 256, 0, stream>>>(z, embed, cnt, candg, out, ws);
    vq_new_embed<<<4096, 256, 0, stream>>>(out, ws);
}